// Round 1
// baseline (420.971 us; speedup 1.0000x reference)
//
#include <hip/hip_runtime.h>
#include <math.h>

#define N_NODES   16000
#define N_EDGES   512000
#define EMBED_DIM 28
#define NODE_DIM  128
#define NUM_BASIS 20

// ---------------------------------------------------------------------------
// x_scalar[node][d] = dot(embed_table[at_no[node]], W[d]) + b[d]
// one thread per output element; writes coalesced.
// ---------------------------------------------------------------------------
__global__ __launch_bounds__(256) void node_kernel(
    const int*   __restrict__ at_no,
    const float* __restrict__ embed,
    const float* __restrict__ W,
    const float* __restrict__ b,
    float*       __restrict__ out)
{
    int idx = blockIdx.x * 256 + threadIdx.x;
    if (idx >= N_NODES * NODE_DIM) return;
    int node = idx >> 7;          // /128
    int d    = idx & 127;
    int a    = at_no[node];
    const float* er = embed + a * EMBED_DIM;
    const float* wr = W + d * EMBED_DIM;
    float sum = b[d];
#pragma unroll
    for (int k = 0; k < EMBED_DIM; ++k)
        sum = fmaf(er[k], wr[k], sum);
    out[idx] = sum;
}

// ---------------------------------------------------------------------------
// Per-edge: dist, rbf(20), fcut(1), rsh(480).
// 2 edges per 256-thread block; 128 threads per edge.
// rsh row = [1.0 x128 | sh1-pattern x192 | sh2-pattern x160], float4 writes.
// Pattern boundaries (128, 320) are float4-aligned.
// ---------------------------------------------------------------------------
__global__ __launch_bounds__(256) void edge_kernel(
    const float* __restrict__ pos,
    const int*   __restrict__ eidx,
    float*       __restrict__ rbf,
    float*       __restrict__ fcut,
    float*       __restrict__ rsh)
{
    const int sub = threadIdx.x >> 7;   // which edge within the block (0/1)
    const int t   = threadIdx.x & 127;  // lane within the edge's 128 threads
    const int e   = blockIdx.x * 2 + sub;   // grid == N_EDGES/2 exactly

    int s  = eidx[e];
    int dn = eidx[N_EDGES + e];

    // reference permutes pos columns by [1,2,0] before the subtraction
    float ax = pos[s*3+1],  ay = pos[s*3+2],  az = pos[s*3+0];
    float bx = pos[dn*3+1], by = pos[dn*3+2], bz = pos[dn*3+0];
    float vx = ax - bx, vy = ay - by, vz = az - bz;
    float d2   = vx*vx + vy*vy + vz*vz;
    float dist = sqrtf(d2);
    float inv  = 1.0f / dist;
    float ux = vx*inv, uy = vy*inv, uz = vz*inv;

    const float S3  = 1.7320508075688772f;
    const float S5  = 2.2360679774997896f;
    const float S15 = 3.8729833462074170f;

    __shared__ float shv[2][8];
    if (t == 0) {
        shv[sub][0] = S3 * ux;
        shv[sub][1] = S3 * uy;
        shv[sub][2] = S3 * uz;
        shv[sub][3] = S15 * ux * uz;
        shv[sub][4] = S15 * ux * uy;
        shv[sub][5] = S5  * (uy*uy - 0.5f*(ux*ux + uz*uz));
        shv[sub][6] = S15 * uy * uz;
        shv[sub][7] = 0.5f * S15 * (uz*uz - ux*ux);
    }
    __syncthreads();

    if (t < NUM_BASIS) {
        // sqrt(2/5) * sin(n*pi*dist/5) / dist
        float arg = (float)(t + 1) * (3.14159265358979323846f / 5.0f) * dist;
        rbf[e * NUM_BASIS + t] = 0.6324555320336759f * sinf(arg) * inv;
    } else if (t == NUM_BASIS) {
        // polynomial cutoff, p=5: 1 - 21 u^5 + 35 u^6 - 15 u^7 for u<1
        float u  = dist * 0.2f;
        float u2 = u * u;
        float u5 = u2 * u2 * u;
        float f  = 1.0f + u5 * (-21.0f + u * (35.0f - 15.0f * u));
        fcut[e] = (u < 1.0f) ? f : 0.0f;
    }

    if (t < 120) {
        int c0 = 4 * t;               // starting column of this float4
        float4 v;
        if (c0 < 128) {
            v = make_float4(1.0f, 1.0f, 1.0f, 1.0f);
        } else if (c0 < 320) {
            int r = (c0 - 128) % 3;
            v.x = shv[sub][r];
            v.y = shv[sub][(r + 1) % 3];
            v.z = shv[sub][(r + 2) % 3];
            v.w = shv[sub][r];        // (r+3)%3 == r
        } else {
            int r = (c0 - 320) % 5;
            v.x = shv[sub][3 + r];
            v.y = shv[sub][3 + (r + 1) % 5];
            v.z = shv[sub][3 + (r + 2) % 5];
            v.w = shv[sub][3 + (r + 3) % 5];
        }
        reinterpret_cast<float4*>(rsh + (size_t)e * 480)[t] = v;
    }
}

extern "C" void kernel_launch(void* const* d_in, const int* in_sizes, int n_in,
                              void* d_out, int out_size, void* d_ws, size_t ws_size,
                              hipStream_t stream) {
    const int*   at_no = (const int*)  d_in[0];
    const float* pos   = (const float*)d_in[1];
    const int*   eidx  = (const int*)  d_in[2];
    const float* embed = (const float*)d_in[3];
    const float* W     = (const float*)d_in[4];
    const float* b     = (const float*)d_in[5];

    float* out      = (float*)d_out;
    float* x_scalar = out;                                   // 16000*128
    float* rbf      = x_scalar + (size_t)N_NODES * NODE_DIM; // 512000*20
    float* fcut     = rbf + (size_t)N_EDGES * NUM_BASIS;     // 512000
    float* rsh      = fcut + N_EDGES;                        // 512000*480

    node_kernel<<<(N_NODES * NODE_DIM + 255) / 256, 256, 0, stream>>>(
        at_no, embed, W, b, x_scalar);

    edge_kernel<<<N_EDGES / 2, 256, 0, stream>>>(
        pos, eidx, rbf, fcut, rsh);
}

// Round 2
// 287.486 us; speedup vs baseline: 1.4643x; 1.4643x over previous
//
#include <hip/hip_runtime.h>
#include <math.h>

#define N_NODES   16000
#define N_EDGES   512000
#define EMBED_DIM 28
#define NODE_DIM  128
#define NUM_BASIS 20

// ---------------------------------------------------------------------------
// x_scalar[node][d] = dot(embed_table[at_no[node]], W[d]) + b[d]
// ---------------------------------------------------------------------------
__global__ __launch_bounds__(256) void node_kernel(
    const int*   __restrict__ at_no,
    const float* __restrict__ embed,
    const float* __restrict__ W,
    const float* __restrict__ b,
    float*       __restrict__ out)
{
    int idx = blockIdx.x * 256 + threadIdx.x;
    if (idx >= N_NODES * NODE_DIM) return;
    int node = idx >> 7;
    int d    = idx & 127;
    int a    = at_no[node];
    const float* er = embed + a * EMBED_DIM;
    const float* wr = W + d * EMBED_DIM;
    float sum = b[d];
#pragma unroll
    for (int k = 0; k < EMBED_DIM; ++k)
        sum = fmaf(er[k], wr[k], sum);
    out[idx] = sum;
}

// ---------------------------------------------------------------------------
// Kernel A: one thread per edge. dist -> fcut, rbf (sin recurrence), shv[8].
// ---------------------------------------------------------------------------
__global__ __launch_bounds__(256) void edge_scalar_kernel(
    const float* __restrict__ pos,
    const int*   __restrict__ eidx,
    float*       __restrict__ rbf,
    float*       __restrict__ fcut,
    float4*      __restrict__ shv)
{
    int e = blockIdx.x * 256 + threadIdx.x;
    if (e >= N_EDGES) return;
    int s  = eidx[e];
    int dn = eidx[N_EDGES + e];

    // reference permutes pos columns by [1,2,0]
    float ax = pos[s*3+1],  ay = pos[s*3+2],  az = pos[s*3+0];
    float bx = pos[dn*3+1], by = pos[dn*3+2], bz = pos[dn*3+0];
    float vx = ax - bx, vy = ay - by, vz = az - bz;
    float dist = sqrtf(vx*vx + vy*vy + vz*vz);
    float inv  = 1.0f / dist;
    float ux = vx*inv, uy = vy*inv, uz = vz*inv;

    const float S3  = 1.7320508075688772f;
    const float S5  = 2.2360679774997896f;
    const float S15 = 3.8729833462074170f;
    shv[2*e]   = make_float4(S3*ux, S3*uy, S3*uz, S15*ux*uz);
    shv[2*e+1] = make_float4(S15*ux*uy,
                             S5*(uy*uy - 0.5f*(ux*ux + uz*uz)),
                             S15*uy*uz,
                             0.5f*S15*(uz*uz - ux*ux));

    // cutoff poly p=5: 1 - 21u^5 + 35u^6 - 15u^7
    float u  = dist * 0.2f;
    float u2 = u*u, u5 = u2*u2*u;
    float f  = 1.0f + u5*(-21.0f + u*(35.0f - 15.0f*u));
    fcut[e] = (u < 1.0f) ? f : 0.0f;

    // rbf[n] = sqrt(2/5) * sin(n*pi*dist/5) / dist, n=1..20 via recurrence
    float th = 0.62831853071795864769f * dist;   // pi/5 * dist
    float s1 = __sinf(th), c1 = __cosf(th);
    float twoc = 2.0f * c1;
    float k = 0.6324555320336759f * inv;
    float sp = 0.0f, sc = s1;
    float4 r0, r1, r2, r3, r4v;
    float4* acc[1]; (void)acc;
#define STEP4(R)                                             \
    {   float v0 = k * sc; float nx;                         \
        nx = twoc*sc - sp; sp = sc; sc = nx; float v1 = k*sc;\
        nx = twoc*sc - sp; sp = sc; sc = nx; float v2 = k*sc;\
        nx = twoc*sc - sp; sp = sc; sc = nx; float v3 = k*sc;\
        nx = twoc*sc - sp; sp = sc; sc = nx;                 \
        R = make_float4(v0, v1, v2, v3); }
    STEP4(r0); STEP4(r1); STEP4(r2); STEP4(r3); STEP4(r4v);
#undef STEP4
    float4* ro = (float4*)(rbf + (size_t)e * NUM_BASIS);
    ro[0] = r0; ro[1] = r1; ro[2] = r2; ro[3] = r3; ro[4] = r4v;
}

// ---------------------------------------------------------------------------
// Kernel B: pure streaming writer for rsh (512000 x 480 f32 = 61.44M float4).
// row layout: [ones x32 f4 | sh1 pattern x48 f4 | sh2 pattern x40 f4]
// ---------------------------------------------------------------------------
__global__ __launch_bounds__(256) void rsh_kernel(
    const float4* __restrict__ shv,
    float4*       __restrict__ rsh)
{
    const unsigned TOTAL = (unsigned)N_EDGES * 120u;
    unsigned stride = gridDim.x * 256u;
    for (unsigned g = blockIdx.x * 256u + threadIdx.x; g < TOTAL; g += stride) {
        unsigned e = g / 120u;
        unsigned c = g - e * 120u;
        float4 v;
        if (c < 32u) {
            v = make_float4(1.0f, 1.0f, 1.0f, 1.0f);
        } else {
            float4 a = shv[2u*e];
            float4 b = shv[2u*e + 1u];
            if (c < 80u) {
                unsigned r = (c - 32u) % 3u;       // (4c-128)%3 == (c-32)%3
                float s0 = a.x, s1 = a.y, s2 = a.z;
                v.x = (r == 0u) ? s0 : (r == 1u) ? s1 : s2;
                v.y = (r == 0u) ? s1 : (r == 1u) ? s2 : s0;
                v.z = (r == 0u) ? s2 : (r == 1u) ? s0 : s1;
                v.w = v.x;
            } else {
                unsigned r = (4u * (c - 80u)) % 5u; // (4c-320)%5
                float t0 = a.w, t1 = b.x, t2 = b.y, t3 = b.z, t4 = b.w;
                v.x = (r==0u)?t0 : (r==1u)?t1 : (r==2u)?t2 : (r==3u)?t3 : t4;
                v.y = (r==0u)?t1 : (r==1u)?t2 : (r==2u)?t3 : (r==3u)?t4 : t0;
                v.z = (r==0u)?t2 : (r==1u)?t3 : (r==2u)?t4 : (r==3u)?t0 : t1;
                v.w = (r==0u)?t3 : (r==1u)?t4 : (r==2u)?t0 : (r==3u)?t1 : t2;
            }
        }
        rsh[g] = v;
    }
}

// ---------------------------------------------------------------------------
// Fallback (round-1 structure) if ws is too small for shv.
// ---------------------------------------------------------------------------
__global__ __launch_bounds__(256) void edge_kernel_fb(
    const float* __restrict__ pos,
    const int*   __restrict__ eidx,
    float*       __restrict__ rbf,
    float*       __restrict__ fcut,
    float*       __restrict__ rsh)
{
    const int sub = threadIdx.x >> 7;
    const int t   = threadIdx.x & 127;
    const int e   = blockIdx.x * 2 + sub;

    int s  = eidx[e];
    int dn = eidx[N_EDGES + e];
    float ax = pos[s*3+1],  ay = pos[s*3+2],  az = pos[s*3+0];
    float bx = pos[dn*3+1], by = pos[dn*3+2], bz = pos[dn*3+0];
    float vx = ax - bx, vy = ay - by, vz = az - bz;
    float dist = sqrtf(vx*vx + vy*vy + vz*vz);
    float inv  = 1.0f / dist;
    float ux = vx*inv, uy = vy*inv, uz = vz*inv;

    const float S3  = 1.7320508075688772f;
    const float S5  = 2.2360679774997896f;
    const float S15 = 3.8729833462074170f;

    __shared__ float shv[2][8];
    if (t == 0) {
        shv[sub][0] = S3 * ux;  shv[sub][1] = S3 * uy;  shv[sub][2] = S3 * uz;
        shv[sub][3] = S15 * ux * uz;  shv[sub][4] = S15 * ux * uy;
        shv[sub][5] = S5  * (uy*uy - 0.5f*(ux*ux + uz*uz));
        shv[sub][6] = S15 * uy * uz;
        shv[sub][7] = 0.5f * S15 * (uz*uz - ux*ux);
    }
    __syncthreads();

    if (t < NUM_BASIS) {
        float arg = (float)(t + 1) * 0.62831853071795864769f * dist;
        rbf[e * NUM_BASIS + t] = 0.6324555320336759f * __sinf(arg) * inv;
    } else if (t == NUM_BASIS) {
        float u  = dist * 0.2f;
        float u2 = u * u, u5 = u2 * u2 * u;
        float f  = 1.0f + u5 * (-21.0f + u * (35.0f - 15.0f * u));
        fcut[e] = (u < 1.0f) ? f : 0.0f;
    }
    if (t < 120) {
        int c0 = 4 * t;
        float4 v;
        if (c0 < 128) v = make_float4(1.0f, 1.0f, 1.0f, 1.0f);
        else if (c0 < 320) {
            int r = (c0 - 128) % 3;
            v.x = shv[sub][r]; v.y = shv[sub][(r+1)%3];
            v.z = shv[sub][(r+2)%3]; v.w = shv[sub][r];
        } else {
            int r = (c0 - 320) % 5;
            v.x = shv[sub][3 + r];         v.y = shv[sub][3 + (r+1)%5];
            v.z = shv[sub][3 + (r+2)%5];   v.w = shv[sub][3 + (r+3)%5];
        }
        reinterpret_cast<float4*>(rsh + (size_t)e * 480)[t] = v;
    }
}

extern "C" void kernel_launch(void* const* d_in, const int* in_sizes, int n_in,
                              void* d_out, int out_size, void* d_ws, size_t ws_size,
                              hipStream_t stream) {
    const int*   at_no = (const int*)  d_in[0];
    const float* pos   = (const float*)d_in[1];
    const int*   eidx  = (const int*)  d_in[2];
    const float* embed = (const float*)d_in[3];
    const float* W     = (const float*)d_in[4];
    const float* b     = (const float*)d_in[5];

    float* out      = (float*)d_out;
    float* x_scalar = out;                                   // 16000*128
    float* rbf      = x_scalar + (size_t)N_NODES * NODE_DIM; // 512000*20
    float* fcut     = rbf + (size_t)N_EDGES * NUM_BASIS;     // 512000
    float* rsh      = fcut + N_EDGES;                        // 512000*480

    node_kernel<<<(N_NODES * NODE_DIM + 255) / 256, 256, 0, stream>>>(
        at_no, embed, W, b, x_scalar);

    const size_t shv_bytes = (size_t)N_EDGES * 8 * sizeof(float);
    if (ws_size >= shv_bytes) {
        float4* shv = (float4*)d_ws;
        edge_scalar_kernel<<<(N_EDGES + 255) / 256, 256, 0, stream>>>(
            pos, eidx, rbf, fcut, shv);
        rsh_kernel<<<2048, 256, 0, stream>>>(shv, (float4*)rsh);
    } else {
        edge_kernel_fb<<<N_EDGES / 2, 256, 0, stream>>>(
            pos, eidx, rbf, fcut, rsh);
    }
}

// Round 4
// 241.992 us; speedup vs baseline: 1.7396x; 1.1880x over previous
//
#include <hip/hip_runtime.h>
#include <math.h>

#define N_NODES   16000
#define N_EDGES   512000
#define EMBED_DIM 28
#define NODE_DIM  128
#define NUM_BASIS 20

// rsh_kernel grid: RSH_BLOCKS * 256 threads, each owns a fixed column of the
// 120-float4 row and strides over edges.
#define RSH_BLOCKS 2040
#define RSH_THREADS (RSH_BLOCKS * 256)
#define RSH_ROWSTRIDE (RSH_THREADS / 120)   // 4352 edges per sweep

typedef float f32x4 __attribute__((ext_vector_type(4)));

// ---------------------------------------------------------------------------
// x_scalar[node][d] = dot(embed_table[at_no[node]], W[d]) + b[d]
// ---------------------------------------------------------------------------
__global__ __launch_bounds__(256) void node_kernel(
    const int*   __restrict__ at_no,
    const float* __restrict__ embed,
    const float* __restrict__ W,
    const float* __restrict__ b,
    float*       __restrict__ out)
{
    int idx = blockIdx.x * 256 + threadIdx.x;
    if (idx >= N_NODES * NODE_DIM) return;
    int node = idx >> 7;
    int d    = idx & 127;
    int a    = at_no[node];
    const float* er = embed + a * EMBED_DIM;
    const float* wr = W + d * EMBED_DIM;
    float sum = b[d];
#pragma unroll
    for (int k = 0; k < EMBED_DIM; ++k)
        sum = fmaf(er[k], wr[k], sum);
    out[idx] = sum;
}

// ---------------------------------------------------------------------------
// Kernel A: one thread per edge. dist -> fcut, rbf (sin recurrence),
// shv12[12] = [1.0, S3ux, S3uy, S3uz, t0, t1, t2, t3, t4, 0, 0, 0]
// ---------------------------------------------------------------------------
__global__ __launch_bounds__(256) void edge_scalar_kernel(
    const float* __restrict__ pos,
    const int*   __restrict__ eidx,
    float*       __restrict__ rbf,
    float*       __restrict__ fcut,
    float4*      __restrict__ shv12)   // 3 float4 per edge
{
    int e = blockIdx.x * 256 + threadIdx.x;
    if (e >= N_EDGES) return;
    int s  = eidx[e];
    int dn = eidx[N_EDGES + e];

    // reference permutes pos columns by [1,2,0]
    float ax = pos[s*3+1],  ay = pos[s*3+2],  az = pos[s*3+0];
    float bx = pos[dn*3+1], by = pos[dn*3+2], bz = pos[dn*3+0];
    float vx = ax - bx, vy = ay - by, vz = az - bz;
    float dist = sqrtf(vx*vx + vy*vy + vz*vz);
    float inv  = 1.0f / dist;
    float ux = vx*inv, uy = vy*inv, uz = vz*inv;

    const float S3  = 1.7320508075688772f;
    const float S5  = 2.2360679774997896f;
    const float S15 = 3.8729833462074170f;
    float t0 = S15 * ux * uz;
    float t1 = S15 * ux * uy;
    float t2 = S5  * (uy*uy - 0.5f*(ux*ux + uz*uz));
    float t3 = S15 * uy * uz;
    float t4 = 0.5f * S15 * (uz*uz - ux*ux);

    shv12[3*e]   = make_float4(1.0f, S3*ux, S3*uy, S3*uz);
    shv12[3*e+1] = make_float4(t0, t1, t2, t3);
    shv12[3*e+2] = make_float4(t4, 0.0f, 0.0f, 0.0f);

    // cutoff poly p=5: 1 - 21u^5 + 35u^6 - 15u^7
    float u  = dist * 0.2f;
    float u2 = u*u, u5 = u2*u2*u;
    float f  = 1.0f + u5*(-21.0f + u*(35.0f - 15.0f*u));
    fcut[e] = (u < 1.0f) ? f : 0.0f;

    // rbf[n] = sqrt(2/5) * sin(n*pi*dist/5) / dist, n=1..20 via recurrence
    float th = 0.62831853071795864769f * dist;   // pi/5 * dist
    float s1 = __sinf(th), c1 = __cosf(th);
    float twoc = 2.0f * c1;
    float k = 0.6324555320336759f * inv;
    float sp = 0.0f, sc = s1;
    float4 r0, r1, r2, r3, r4v;
#define STEP4(R)                                             \
    {   float v0 = k * sc; float nx;                         \
        nx = twoc*sc - sp; sp = sc; sc = nx; float v1 = k*sc;\
        nx = twoc*sc - sp; sp = sc; sc = nx; float v2 = k*sc;\
        nx = twoc*sc - sp; sp = sc; sc = nx; float v3 = k*sc;\
        nx = twoc*sc - sp; sp = sc; sc = nx;                 \
        R = make_float4(v0, v1, v2, v3); }
    STEP4(r0); STEP4(r1); STEP4(r2); STEP4(r3); STEP4(r4v);
#undef STEP4
    float4* ro = (float4*)(rbf + (size_t)e * NUM_BASIS);
    ro[0] = r0; ro[1] = r1; ro[2] = r2; ro[3] = r3; ro[4] = r4v;
}

// ---------------------------------------------------------------------------
// Kernel B: streaming writer for rsh. Thread owns fixed column c (float4 slot)
// of the 120-f4 row; its 4 component selectors j0..j3 into the 12-float shv
// row are loop-invariant. Inner loop: 4 L1-broadcast loads + 1 nt store.
// ---------------------------------------------------------------------------
__global__ __launch_bounds__(256) void rsh_kernel(
    const float* __restrict__ shv12,
    float*       __restrict__ rsh)
{
    int g    = blockIdx.x * 256 + threadIdx.x;
    int row0 = g / 120;
    int c    = g - row0 * 120;

    // selector for component k of float4 slot c (column = 4c+k):
    //   col < 128          -> 0          (the 1.0 slot)
    //   128 <= col < 320   -> 1 + (col-128)%3
    //   col >= 320         -> 4 + (col-320)%5
    int j[4];
#pragma unroll
    for (int k = 0; k < 4; ++k) {
        int col = 4 * c + k;
        int jj;
        if (col < 128)      jj = 0;
        else if (col < 320) jj = 1 + (col - 128) % 3;
        else                jj = 4 + (col - 320) % 5;
        j[k] = jj;
    }

    const float* base = shv12 + 12 * row0;
    const int j0 = j[0], j1 = j[1], j2 = j[2], j3 = j[3];
    float* outp = rsh + (size_t)row0 * 480 + 4 * c;

    for (int e = row0; e < N_EDGES; e += RSH_ROWSTRIDE) {
        f32x4 v;
        v.x = base[j0]; v.y = base[j1]; v.z = base[j2]; v.w = base[j3];
        __builtin_nontemporal_store(v, (f32x4*)outp);
        base += 12 * RSH_ROWSTRIDE;
        outp += 480 * RSH_ROWSTRIDE;
    }
}

// ---------------------------------------------------------------------------
// Fallback (round-1 structure) if ws is too small for shv12.
// ---------------------------------------------------------------------------
__global__ __launch_bounds__(256) void edge_kernel_fb(
    const float* __restrict__ pos,
    const int*   __restrict__ eidx,
    float*       __restrict__ rbf,
    float*       __restrict__ fcut,
    float*       __restrict__ rsh)
{
    const int sub = threadIdx.x >> 7;
    const int t   = threadIdx.x & 127;
    const int e   = blockIdx.x * 2 + sub;

    int s  = eidx[e];
    int dn = eidx[N_EDGES + e];
    float ax = pos[s*3+1],  ay = pos[s*3+2],  az = pos[s*3+0];
    float bx = pos[dn*3+1], by = pos[dn*3+2], bz = pos[dn*3+0];
    float vx = ax - bx, vy = ay - by, vz = az - bz;
    float dist = sqrtf(vx*vx + vy*vy + vz*vz);
    float inv  = 1.0f / dist;
    float ux = vx*inv, uy = vy*inv, uz = vz*inv;

    const float S3  = 1.7320508075688772f;
    const float S5  = 2.2360679774997896f;
    const float S15 = 3.8729833462074170f;

    __shared__ float shv[2][8];
    if (t == 0) {
        shv[sub][0] = S3 * ux;  shv[sub][1] = S3 * uy;  shv[sub][2] = S3 * uz;
        shv[sub][3] = S15 * ux * uz;  shv[sub][4] = S15 * ux * uy;
        shv[sub][5] = S5  * (uy*uy - 0.5f*(ux*ux + uz*uz));
        shv[sub][6] = S15 * uy * uz;
        shv[sub][7] = 0.5f * S15 * (uz*uz - ux*ux);
    }
    __syncthreads();

    if (t < NUM_BASIS) {
        float arg = (float)(t + 1) * 0.62831853071795864769f * dist;
        rbf[e * NUM_BASIS + t] = 0.6324555320336759f * __sinf(arg) * inv;
    } else if (t == NUM_BASIS) {
        float u  = dist * 0.2f;
        float u2 = u * u, u5 = u2 * u2 * u;
        float f  = 1.0f + u5 * (-21.0f + u * (35.0f - 15.0f * u));
        fcut[e] = (u < 1.0f) ? f : 0.0f;
    }
    if (t < 120) {
        int c0 = 4 * t;
        float4 v;
        if (c0 < 128) v = make_float4(1.0f, 1.0f, 1.0f, 1.0f);
        else if (c0 < 320) {
            int r = (c0 - 128) % 3;
            v.x = shv[sub][r]; v.y = shv[sub][(r+1)%3];
            v.z = shv[sub][(r+2)%3]; v.w = shv[sub][r];
        } else {
            int r = (c0 - 320) % 5;
            v.x = shv[sub][3 + r];         v.y = shv[sub][3 + (r+1)%5];
            v.z = shv[sub][3 + (r+2)%5];   v.w = shv[sub][3 + (r+3)%5];
        }
        reinterpret_cast<float4*>(rsh + (size_t)e * 480)[t] = v;
    }
}

extern "C" void kernel_launch(void* const* d_in, const int* in_sizes, int n_in,
                              void* d_out, int out_size, void* d_ws, size_t ws_size,
                              hipStream_t stream) {
    const int*   at_no = (const int*)  d_in[0];
    const float* pos   = (const float*)d_in[1];
    const int*   eidx  = (const int*)  d_in[2];
    const float* embed = (const float*)d_in[3];
    const float* W     = (const float*)d_in[4];
    const float* b     = (const float*)d_in[5];

    float* out      = (float*)d_out;
    float* x_scalar = out;                                   // 16000*128
    float* rbf      = x_scalar + (size_t)N_NODES * NODE_DIM; // 512000*20
    float* fcut     = rbf + (size_t)N_EDGES * NUM_BASIS;     // 512000
    float* rsh      = fcut + N_EDGES;                        // 512000*480

    node_kernel<<<(N_NODES * NODE_DIM + 255) / 256, 256, 0, stream>>>(
        at_no, embed, W, b, x_scalar);

    const size_t shv_bytes = (size_t)N_EDGES * 12 * sizeof(float);
    if (ws_size >= shv_bytes) {
        float4* shv12 = (float4*)d_ws;
        edge_scalar_kernel<<<(N_EDGES + 255) / 256, 256, 0, stream>>>(
            pos, eidx, rbf, fcut, shv12);
        rsh_kernel<<<RSH_BLOCKS, 256, 0, stream>>>((const float*)d_ws, rsh);
    } else {
        edge_kernel_fb<<<N_EDGES / 2, 256, 0, stream>>>(
            pos, eidx, rbf, fcut, rsh);
    }
}